// Round 1
// baseline (478.394 us; speedup 1.0000x reference)
//
#include <hip/hip_runtime.h>
#include <math.h>

// Problem constants
#define B_      32
#define C_IN    64
#define H_      4096
#define F_      8
#define OUT_CH  9          // F+1
#define KW      5          // F/2+1
#define BH      (B_ * H_)  // 131072 independent (b,h) problems
#define LOC_N   (BH * F_)  // 1048576 floats of loc output
#define NSWEEP  6
#define MIN_VEC 0.001f

__device__ __forceinline__ float softplus_f(float v) {
    // stable: max(v,0) + log(1+exp(-|v|))
    return fmaxf(v, 0.0f) + __logf(1.0f + __expf(-fabsf(v)));
}

__global__ __launch_bounds__(256, 2)
void mgauss_fused(const float* __restrict__ x,
                  const float* __restrict__ w_n,
                  const float* __restrict__ b_n,
                  const float* __restrict__ w_p,
                  const float* __restrict__ b_p,
                  float* __restrict__ out)
{
    const int t = blockIdx.x * 256 + threadIdx.x;   // grid sized exactly BH
    const int b = t >> 12;          // /4096
    const int h = t & 4095;

    // x[b, c, h, w] at ((b*64 + c)*4096 + h)*8 + w ; per-c stride = 32768 floats
    const float* xp = x + ((size_t)b * C_IN * H_ + h) * F_;

    float la[F_];
    #pragma unroll
    for (int w = 0; w < F_; ++w) la[w] = 0.0f;
    float pa[OUT_CH][4];
    #pragma unroll
    for (int o = 0; o < OUT_CH; ++o)
        #pragma unroll
        for (int wo = 0; wo < 4; ++wo) pa[o][wo] = 0.0f;

    #pragma unroll 2
    for (int c = 0; c < C_IN; ++c) {
        const float4 x0 = *(const float4*)(xp + (size_t)c * (H_ * F_));
        const float4 x1 = *(const float4*)(xp + (size_t)c * (H_ * F_) + 4);
        const float xa[F_] = {x0.x, x0.y, x0.z, x0.w, x1.x, x1.y, x1.z, x1.w};

        const float wn = w_n[c];   // wave-uniform -> s_load
        #pragma unroll
        for (int w = 0; w < F_; ++w) la[w] = fmaf(xa[w], wn, la[w]);

        #pragma unroll
        for (int o = 0; o < OUT_CH; ++o) {
            #pragma unroll
            for (int k = 0; k < KW; ++k) {
                const float wv = w_p[(o * C_IN + c) * KW + k];  // uniform -> s_load
                #pragma unroll
                for (int wo = 0; wo < 4; ++wo)
                    pa[o][wo] = fmaf(xa[wo + k], wv, pa[o][wo]);
            }
        }
    }

    // ---- loc output: softplus(conv1x1 + b_n), layout [B,1,H,8] -> t*8+w
    {
        const float bn = b_n[0];
        float lv[F_];
        #pragma unroll
        for (int w = 0; w < F_; ++w) lv[w] = softplus_f(la[w] + bn);
        float* lo = out + (size_t)t * F_;
        *(float4*)(lo)     = make_float4(lv[0], lv[1], lv[2], lv[3]);
        *(float4*)(lo + 4) = make_float4(lv[4], lv[5], lv[6], lv[7]);
    }

    // ---- build symmetric A from sigma (k = o*4+wo scattered to upper-tri row-major)
    float sig[36];
    #pragma unroll
    for (int o = 0; o < OUT_CH; ++o) {
        const float bp = b_p[o];
        #pragma unroll
        for (int wo = 0; wo < 4; ++wo)
            sig[o * 4 + wo] = softplus_f(pa[o][wo] + bp);
    }

    float A[F_][F_];
    {
        int k = 0;
        #pragma unroll
        for (int i = 0; i < F_; ++i)
            #pragma unroll
            for (int j = i; j < F_; ++j) {
                A[i][j] = sig[k];
                A[j][i] = sig[k];
                ++k;
            }
    }

    float V[F_][F_];
    #pragma unroll
    for (int i = 0; i < F_; ++i)
        #pragma unroll
        for (int j = 0; j < F_; ++j)
            V[i][j] = (i == j) ? 1.0f : 0.0f;

    // ---- cyclic Jacobi, fully unrolled pairs (static indices -> stays in VGPRs)
    for (int sweep = 0; sweep < NSWEEP; ++sweep) {
        #pragma unroll
        for (int p = 0; p < F_ - 1; ++p) {
            #pragma unroll
            for (int q = p + 1; q < F_; ++q) {
                const float apq = A[p][q];
                const float app = A[p][p];
                const float aqq = A[q][q];
                float th = (aqq - app) / (2.0f * apq);
                float tt = 1.0f / (fabsf(th) + sqrtf(fmaf(th, th, 1.0f)));
                tt = (th < 0.0f) ? -tt : tt;
                tt = (apq == 0.0f) ? 0.0f : tt;   // also kills NaN from 0/0
                const float cc = 1.0f / sqrtf(fmaf(tt, tt, 1.0f));
                const float ss = tt * cc;

                // A = R A R^T : rows p,q then cols p,q
                #pragma unroll
                for (int i = 0; i < F_; ++i) {
                    const float u = A[p][i], v = A[q][i];
                    A[p][i] = cc * u - ss * v;
                    A[q][i] = fmaf(ss, u, cc * v);
                }
                #pragma unroll
                for (int i = 0; i < F_; ++i) {
                    const float u = A[i][p], v = A[i][q];
                    A[i][p] = cc * u - ss * v;
                    A[i][q] = fmaf(ss, u, cc * v);
                }
                // V = V R^T (columns of V accumulate eigenvectors)
                #pragma unroll
                for (int i = 0; i < F_; ++i) {
                    const float u = V[i][p], v = V[i][q];
                    V[i][p] = cc * u - ss * v;
                    V[i][q] = fmaf(ss, u, cc * v);
                }
            }
        }
    }

    // ---- reconstruct PD = V * max(diag(A), MIN_VEC) * V^T (exactly symmetric)
    float lam[F_];
    #pragma unroll
    for (int k = 0; k < F_; ++k) lam[k] = fmaxf(A[k][k], MIN_VEC);

    float W[F_][F_];
    #pragma unroll
    for (int i = 0; i < F_; ++i)
        #pragma unroll
        for (int k = 0; k < F_; ++k)
            W[i][k] = V[i][k] * lam[k];

    float PD[F_][F_];
    #pragma unroll
    for (int i = 0; i < F_; ++i) {
        #pragma unroll
        for (int j = i; j < F_; ++j) {
            float acc = 0.0f;
            #pragma unroll
            for (int k = 0; k < F_; ++k)
                acc = fmaf(W[i][k], V[j][k], acc);
            PD[i][j] = acc;
            PD[j][i] = acc;
        }
    }

    float* po = out + LOC_N + (size_t)t * (F_ * F_);
    #pragma unroll
    for (int i = 0; i < F_; ++i) {
        *(float4*)(po + i * F_)     = make_float4(PD[i][0], PD[i][1], PD[i][2], PD[i][3]);
        *(float4*)(po + i * F_ + 4) = make_float4(PD[i][4], PD[i][5], PD[i][6], PD[i][7]);
    }
}

extern "C" void kernel_launch(void* const* d_in, const int* in_sizes, int n_in,
                              void* d_out, int out_size, void* d_ws, size_t ws_size,
                              hipStream_t stream) {
    const float* x   = (const float*)d_in[0];
    const float* w_n = (const float*)d_in[1];
    const float* b_n = (const float*)d_in[2];
    const float* w_p = (const float*)d_in[3];
    const float* b_p = (const float*)d_in[4];
    float* out = (float*)d_out;

    dim3 grid(BH / 256);
    dim3 block(256);
    hipLaunchKernelGGL(mgauss_fused, grid, block, 0, stream,
                       x, w_n, b_n, w_p, b_p, out);
}

// Round 2
// 457.997 us; speedup vs baseline: 1.0445x; 1.0445x over previous
//
#include <hip/hip_runtime.h>
#include <math.h>

// Problem constants
#define B_      32
#define C_IN    64
#define H_      4096
#define F_      8
#define OUT_CH  9          // F+1
#define KW      5          // F/2+1
#define BH      (B_ * H_)  // 131072 independent (b,h) problems
#define LOC_N   (BH * F_)  // 1048576 floats of loc output
#define NSWEEP  6
#define MIN_VEC 0.001f

// Tournament (round-robin) parallel-Jacobi ordering: 7 rounds x 4 disjoint
// pairs covers all 28 (p,q) pairs, p<q. Disjoint rotations commute; angles
// computed from pre-round A still zero each pivot exactly.
__device__ const int PAIRS[7][4][2] = {
  {{0,7},{1,6},{2,5},{3,4}},
  {{0,6},{5,7},{1,4},{2,3}},
  {{0,5},{4,6},{3,7},{1,2}},
  {{0,4},{3,5},{2,6},{1,7}},
  {{0,3},{2,4},{1,5},{6,7}},
  {{0,2},{1,3},{4,7},{5,6}},
  {{0,1},{2,7},{3,6},{4,5}},
};

// Upper-triangle symmetric element access; i,j compile-time constants after
// unrolling, so the select folds away.
#define SYM(i,j) (((i) < (j)) ? A[i][j] : A[j][i])

__device__ __forceinline__ float softplus_f(float v) {
    // stable: max(v,0) + log(1+exp(-|v|))
    return fmaxf(v, 0.0f) + __logf(1.0f + __expf(-fabsf(v)));
}

__global__ __launch_bounds__(256, 2)
void mgauss_fused(const float* __restrict__ x,
                  const float* __restrict__ w_n,
                  const float* __restrict__ b_n,
                  const float* __restrict__ w_p,
                  const float* __restrict__ b_p,
                  float* __restrict__ out)
{
    const int t = blockIdx.x * 256 + threadIdx.x;   // grid sized exactly BH
    const int b = t >> 12;          // /4096
    const int h = t & 4095;

    // x[b, c, h, w] at ((b*64 + c)*4096 + h)*8 + w ; per-c stride = 32768 floats
    const float* xp = x + ((size_t)b * C_IN * H_ + h) * F_;

    float la[F_];
    #pragma unroll
    for (int w = 0; w < F_; ++w) la[w] = 0.0f;
    float pa[OUT_CH][4];
    #pragma unroll
    for (int o = 0; o < OUT_CH; ++o)
        #pragma unroll
        for (int wo = 0; wo < 4; ++wo) pa[o][wo] = 0.0f;

    #pragma unroll 4
    for (int c = 0; c < C_IN; ++c) {
        const float4 x0 = *(const float4*)(xp + (size_t)c * (H_ * F_));
        const float4 x1 = *(const float4*)(xp + (size_t)c * (H_ * F_) + 4);
        const float xa[F_] = {x0.x, x0.y, x0.z, x0.w, x1.x, x1.y, x1.z, x1.w};

        const float wn = w_n[c];   // wave-uniform -> s_load
        #pragma unroll
        for (int w = 0; w < F_; ++w) la[w] = fmaf(xa[w], wn, la[w]);

        #pragma unroll
        for (int o = 0; o < OUT_CH; ++o) {
            #pragma unroll
            for (int k = 0; k < KW; ++k) {
                const float wv = w_p[(o * C_IN + c) * KW + k];  // uniform -> s_load
                #pragma unroll
                for (int wo = 0; wo < 4; ++wo)
                    pa[o][wo] = fmaf(xa[wo + k], wv, pa[o][wo]);
            }
        }
    }

    // ---- loc output: softplus(conv1x1 + b_n), layout [B,1,H,8] -> t*8+w
    {
        const float bn = b_n[0];
        float lv[F_];
        #pragma unroll
        for (int w = 0; w < F_; ++w) lv[w] = softplus_f(la[w] + bn);
        float* lo = out + (size_t)t * F_;
        *(float4*)(lo)     = make_float4(lv[0], lv[1], lv[2], lv[3]);
        *(float4*)(lo + 4) = make_float4(lv[4], lv[5], lv[6], lv[7]);
    }

    // ---- build symmetric A (upper triangle only) from sigma
    // sigma k = o*4+wo scattered to upper-tri row-major: A[i][j], j>=i
    float A[F_][F_];   // only entries j>=i are used/maintained
    {
        float sig[36];
        #pragma unroll
        for (int o = 0; o < OUT_CH; ++o) {
            const float bp = b_p[o];
            #pragma unroll
            for (int wo = 0; wo < 4; ++wo)
                sig[o * 4 + wo] = softplus_f(pa[o][wo] + bp);
        }
        int k = 0;
        #pragma unroll
        for (int i = 0; i < F_; ++i)
            #pragma unroll
            for (int j = i; j < F_; ++j) {
                A[i][j] = sig[k];
                ++k;
            }
    }

    float V[F_][F_];
    #pragma unroll
    for (int i = 0; i < F_; ++i)
        #pragma unroll
        for (int j = 0; j < F_; ++j)
            V[i][j] = (i == j) ? 1.0f : 0.0f;

    // ---- parallel-ordering Jacobi: per round, 4 independent setups (ILP),
    //      then symmetric (upper-tri) A updates + V column updates.
    for (int sweep = 0; sweep < NSWEEP; ++sweep) {
        #pragma unroll
        for (int r = 0; r < 7; ++r) {
            float cs[4], sn[4], tv[4];
            #pragma unroll
            for (int j = 0; j < 4; ++j) {
                const int p = PAIRS[r][j][0], q = PAIRS[r][j][1];
                const float apq = A[p][q];
                const float app = A[p][p];
                const float aqq = A[q][q];
                float th = (aqq - app) / (2.0f * apq);
                float tt = 1.0f / (fabsf(th) + sqrtf(fmaf(th, th, 1.0f)));
                tt = (th < 0.0f) ? -tt : tt;
                tt = (apq == 0.0f) ? 0.0f : tt;   // kills NaN from 0/0
                const float cc = 1.0f / sqrtf(fmaf(tt, tt, 1.0f));
                cs[j] = cc; sn[j] = tt * cc; tv[j] = tt;
            }
            // A updates: disjoint pairs -> sequential application == R A R^T
            #pragma unroll
            for (int j = 0; j < 4; ++j) {
                const int p = PAIRS[r][j][0], q = PAIRS[r][j][1];
                const float cc = cs[j], ss = sn[j], tt = tv[j];
                const float apq = A[p][q];
                A[p][p] = fmaf(-tt, apq, A[p][p]);
                A[q][q] = fmaf( tt, apq, A[q][q]);
                A[p][q] = 0.0f;
                #pragma unroll
                for (int i = 0; i < F_; ++i) {
                    if (i == p || i == q) continue;
                    const float aip = SYM(i, p);
                    const float aiq = SYM(i, q);
                    SYM(i, p) = fmaf(-ss, aiq, cc * aip);
                    SYM(i, q) = fmaf( ss, aip, cc * aiq);
                }
            }
            // V updates: columns p,q per pair, fully independent across pairs
            #pragma unroll
            for (int j = 0; j < 4; ++j) {
                const int p = PAIRS[r][j][0], q = PAIRS[r][j][1];
                const float cc = cs[j], ss = sn[j];
                #pragma unroll
                for (int i = 0; i < F_; ++i) {
                    const float u = V[i][p], v = V[i][q];
                    V[i][p] = fmaf(-ss, v, cc * u);
                    V[i][q] = fmaf( ss, u, cc * v);
                }
            }
        }
    }

    // ---- reconstruct PD = V * max(diag(A), MIN_VEC) * V^T (exactly symmetric)
    float lam[F_];
    #pragma unroll
    for (int k = 0; k < F_; ++k) lam[k] = fmaxf(A[k][k], MIN_VEC);

    float W[F_][F_];
    #pragma unroll
    for (int i = 0; i < F_; ++i)
        #pragma unroll
        for (int k = 0; k < F_; ++k)
            W[i][k] = V[i][k] * lam[k];

    float PD[F_][F_];
    #pragma unroll
    for (int i = 0; i < F_; ++i) {
        #pragma unroll
        for (int j = i; j < F_; ++j) {
            float acc = 0.0f;
            #pragma unroll
            for (int k = 0; k < F_; ++k)
                acc = fmaf(W[i][k], V[j][k], acc);
            PD[i][j] = acc;
            PD[j][i] = acc;
        }
    }

    float* po = out + LOC_N + (size_t)t * (F_ * F_);
    #pragma unroll
    for (int i = 0; i < F_; ++i) {
        *(float4*)(po + i * F_)     = make_float4(PD[i][0], PD[i][1], PD[i][2], PD[i][3]);
        *(float4*)(po + i * F_ + 4) = make_float4(PD[i][4], PD[i][5], PD[i][6], PD[i][7]);
    }
}

extern "C" void kernel_launch(void* const* d_in, const int* in_sizes, int n_in,
                              void* d_out, int out_size, void* d_ws, size_t ws_size,
                              hipStream_t stream) {
    const float* x   = (const float*)d_in[0];
    const float* w_n = (const float*)d_in[1];
    const float* b_n = (const float*)d_in[2];
    const float* w_p = (const float*)d_in[3];
    const float* b_p = (const float*)d_in[4];
    float* out = (float*)d_out;

    dim3 grid(BH / 256);
    dim3 block(256);
    hipLaunchKernelGGL(mgauss_fused, grid, block, 0, stream,
                       x, w_n, b_n, w_p, b_p, out);
}